// Round 1
// baseline (1316.032 us; speedup 1.0000x reference)
//
#include <hip/hip_runtime.h>

#define Gn 128
#define Tn 512
#define Sn 24
#define SP 28   // padded LDS row stride (16B-aligned)
#define Mn 4
#define COVS_BASE (Gn * Tn * Mn)   // 262144

__device__ __forceinline__ float4 ld4(const float* p) {
    return *reinterpret_cast<const float4*>(p);
}
__device__ __forceinline__ void st4(float* p, float4 v) {
    *reinterpret_cast<float4*>(p) = v;
}
__device__ __forceinline__ float dot4(float4 a, float4 b) {
    return a.x*b.x + a.y*b.y + a.z*b.z + a.w*b.w;
}

struct Row24 { float4 v[6]; };

__device__ __forceinline__ Row24 loadRow(const float* p) {
    Row24 r;
#pragma unroll
    for (int i = 0; i < 6; ++i) r.v[i] = ld4(p + 4*i);
    return r;
}

__device__ __forceinline__ float dot24(const Row24& a, const float* b) {
    float4 b0 = ld4(b+0), b1 = ld4(b+4), b2 = ld4(b+8),
           b3 = ld4(b+12), b4 = ld4(b+16), b5 = ld4(b+20);
    float s0 = dot4(a.v[0], b0);
    float s1 = dot4(a.v[1], b1);
    float s2 = dot4(a.v[2], b2);
    float s3 = dot4(a.v[3], b3);
    float s4 = dot4(a.v[4], b4);
    float s5 = dot4(a.v[5], b5);
    return ((s0+s1)+(s2+s3))+(s4+s5);
}

__device__ __forceinline__ float dot24rr(const Row24& a, const Row24& b) {
    float s0 = dot4(a.v[0], b.v[0]);
    float s1 = dot4(a.v[1], b.v[1]);
    float s2 = dot4(a.v[2], b.v[2]);
    float s3 = dot4(a.v[3], b.v[3]);
    float s4 = dot4(a.v[4], b.v[4]);
    float s5 = dot4(a.v[5], b.v[5]);
    return ((s0+s1)+(s2+s3))+(s4+s5);
}

// Raw barrier: waits only LDS (lgkmcnt), NOT vmcnt -> prefetch global loads stay
// in flight across the barrier.
__device__ __forceinline__ void barrierLds() {
    asm volatile("s_waitcnt lgkmcnt(0)" ::: "memory");
    __builtin_amdgcn_s_barrier();
    asm volatile("" ::: "memory");
}
// Wave-internal LDS RAW ordering (single wave): lockstep HW + lgkm wait.
__device__ __forceinline__ void waveLds() {
    asm volatile("s_waitcnt lgkmcnt(0)" ::: "memory");
    __builtin_amdgcn_wave_barrier();
    asm volatile("" ::: "memory");
}

extern "C" __global__ void __launch_bounds__(256)
kalman_kernel(const float* __restrict__ y_g, const float* __restrict__ F_g,
              const float* __restrict__ Q_g, const float* __restrict__ H_g,
              const float* __restrict__ R_g, const float* __restrict__ m0_g,
              const float* __restrict__ P0_g, float* __restrict__ out)
{
    const int g   = blockIdx.x;
    const int tid = threadIdx.x;
    const int gT  = g * Tn;

    __shared__ __align__(16) float sP[Sn*SP];      // covariance (symmetric)
    __shared__ __align__(16) float sFP[Sn*SP];     // FP = F @ P
    __shared__ __align__(16) float sF[2][Sn*SP];
    __shared__ __align__(16) float sQ[2][Sn*SP];
    __shared__ __align__(16) float sH[2][Mn*SP];
    __shared__ __align__(16) float sR[2][16];
    __shared__ __align__(16) float sy[2][4];
    __shared__ __align__(16) float sHP[Mn*SP];     // H@P rows (4 x 24)
    __shared__ __align__(16) float sW[Sn*4];       // W = FP@H^T rows (24 x 4, 16B rows)
    __shared__ __align__(16) float sSig[16];
    __shared__ __align__(16) float sInv[16];       // Sig^-1 (symmetric)
    __shared__ __align__(16) float sMean[Sn];
    __shared__ __align__(16) float sFm[Sn];        // F @ m
    __shared__ __align__(16) float sResid[4];

    const float4* F4 = reinterpret_cast<const float4*>(F_g);
    const float4* Q4 = reinterpret_cast<const float4*>(Q_g);
    const float4* H4 = reinterpret_cast<const float4*>(H_g);
    const float4* R4 = reinterpret_cast<const float4*>(R_g);
    const float4* y4 = reinterpret_cast<const float4*>(y_g);

    // stage mapping: 317 float4 per step: F 144, Q 144, H 24, R 4, y 1
    auto stage_load = [&](int v, int t) -> float4 {
        if (v < 144)      return F4[(gT + t)*144 + v];
        else if (v < 288) return Q4[(gT + t)*144 + (v-144)];
        else if (v < 312) return H4[(gT + t)*24  + (v-288)];
        else if (v < 316) return R4[(gT + t)*4   + (v-312)];
        else              return y4[gT + t];
    };
    auto stage_store = [&](int v, int bb, float4 val) {
        if (v < 144)      { int r = v/6,        c = (v%6)*4;       st4(&sF[bb][r*SP+c], val); }
        else if (v < 288) { int v2 = v-144; int r = v2/6, c = (v2%6)*4; st4(&sQ[bb][r*SP+c], val); }
        else if (v < 312) { int v2 = v-288; int r = v2/6, c = (v2%6)*4; st4(&sH[bb][r*SP+c], val); }
        else if (v < 316) { st4(&sR[bb][(v-312)*4], val); }
        else              { st4(&sy[bb][0], val); }
    };

    // ---------------- prologue ----------------
    if (tid < 144) {
        int r = tid / 6, c = (tid % 6) * 4;
        st4(&sP[r*SP + c], ld4(&P0_g[g*Sn*Sn + tid*4]));
    } else if (tid < 150) {
        int v = tid - 144;
        st4(&sMean[v*4], ld4(&m0_g[g*Sn + v*4]));
    }
    {   // stage t=0 synchronously
        float4 a0 = stage_load(tid, 0);
        stage_store(tid, 0, a0);
        if (tid + 256 < 317) {
            float4 a1 = stage_load(tid + 256, 0);
            stage_store(tid + 256, 0, a1);
        }
    }
    barrierLds();

    // ---------------- hoisted per-thread indices (t-invariant) ----------------
    const int w    = tid >> 6;
    const int lane = tid & 63;
    const int ib   = lane >> 3, jb = lane & 7;
    const int i0   = 3*ib, j0 = 3*jb;                 // 3x3 tile (w0: FP, w1: A/Pnew)
    const int a2   = lane / 24,        s2 = lane % 24;            // w2 Ph1: HP out o=lane
    const int a3   = (64+lane) / 24,   s3 = (64+lane) % 24;       // w3 Ph1 (lane<32): HP out o=64+lane
    const int iW   = lane >> 1,        aW = (lane & 1) * 2;       // w2 Ph2: W half-rows (lane<48)

    float4 pf0, pf1;

    for (int t = 0; t < Tn; ++t) {
        const int  b    = t & 1;
        const int  b1   = b ^ 1;
        const bool last = (t == Tn - 1);

        // prefetch-issue t+1 (stays in flight across barrierLds)
        if (!last) {
            pf0 = stage_load(tid, t+1);
            if (tid + 256 < 317) pf1 = stage_load(tid + 256, t+1);
        }

        // ---- Phase 1: FP = F@P (w0) ; HP = H@P (w2,w3) ; Fm (w1) ; mu/resid (w3) ----
        if (w == 0) {
            if (!last) {
                Row24 p0r = loadRow(&sP[(j0+0)*SP]);
                Row24 p1r = loadRow(&sP[(j0+1)*SP]);
                Row24 p2r = loadRow(&sP[(j0+2)*SP]);
#pragma unroll
                for (int r = 0; r < 3; ++r) {
                    Row24 fr = loadRow(&sF[b][(i0+r)*SP]);
                    sFP[(i0+r)*SP + j0+0] = dot24rr(fr, p0r);
                    sFP[(i0+r)*SP + j0+1] = dot24rr(fr, p1r);
                    sFP[(i0+r)*SP + j0+2] = dot24rr(fr, p2r);
                }
            }
        } else if (w == 1) {
            if (lane < 24 && !last) {   // Fm = F @ m
                Row24 fr = loadRow(&sF[b][lane*SP]);
                sFm[lane] = dot24(fr, sMean);
            }
        } else if (w == 2) {            // HP outs 0..63
            Row24 hr = loadRow(&sH[b][a2*SP]);
            sHP[a2*SP + s2] = dot24(hr, &sP[s2*SP]);   // P symmetric: col s == row s
        } else {                        // w3
            if (lane < 32) {            // HP outs 64..95
                Row24 hr = loadRow(&sH[b][a3*SP]);
                sHP[a3*SP + s3] = dot24(hr, &sP[s3*SP]);
            } else if (lane < 36) {     // mu + resid (means output)
                int a = lane - 32;
                Row24 hr = loadRow(&sH[b][a*SP]);
                float mu = dot24(hr, sMean);
                out[(gT + t)*4 + a] = mu;
                sResid[a] = sy[b][a] - mu;
            }
        }
        barrierLds();

        // ---- Phase 2: A = FP@F^T (w1, regs) ; W = FP@H^T (w2) ; Sig->Inv (w3) ----
        float acc[3][3];
        if (w == 1) {
            if (!last) {
                Row24 fr0 = loadRow(&sF[b][(j0+0)*SP]);
                Row24 fr1 = loadRow(&sF[b][(j0+1)*SP]);
                Row24 fr2 = loadRow(&sF[b][(j0+2)*SP]);
#pragma unroll
                for (int r = 0; r < 3; ++r) {
                    Row24 fp = loadRow(&sFP[(i0+r)*SP]);
                    acc[r][0] = dot24rr(fp, fr0);
                    acc[r][1] = dot24rr(fp, fr1);
                    acc[r][2] = dot24rr(fp, fr2);
                }
            }
        } else if (w == 2) {
            if (lane < 48 && !last) {
                Row24 fp = loadRow(&sFP[iW*SP]);
                sW[iW*4 + aW]     = dot24(fp, &sH[b][aW*SP]);
                sW[iW*4 + aW + 1] = dot24(fp, &sH[b][(aW+1)*SP]);
            }
        } else if (w == 3) {
            if (lane < 16) {
                int a = lane >> 2, bb = lane & 3;
                Row24 hp = loadRow(&sHP[a*SP]);
                float sig = dot24(hp, &sH[b][bb*SP]) + sR[b][lane];
                sSig[lane] = sig;
                out[COVS_BASE + (size_t)(gT + t)*16 + lane] = sig;  // covs output
            }
            if (!last) {
                waveLds();
                if (lane < 16) {
                    float s00=sSig[0],  s01=sSig[1],  s02=sSig[2],  s03=sSig[3];
                    float s10=sSig[4],  s11=sSig[5],  s12=sSig[6],  s13=sSig[7];
                    float s20=sSig[8],  s21=sSig[9],  s22=sSig[10], s23=sSig[11];
                    float s30=sSig[12], s31=sSig[13], s32=sSig[14], s33=sSig[15];
                    float p0 = s00*s11 - s01*s10;
                    float p1 = s00*s12 - s02*s10;
                    float p2 = s00*s13 - s03*s10;
                    float p3 = s01*s12 - s02*s11;
                    float p4 = s01*s13 - s03*s11;
                    float p5 = s02*s13 - s03*s12;
                    float q0c = s20*s31 - s21*s30;
                    float q1c = s20*s32 - s22*s30;
                    float q2c = s20*s33 - s23*s30;
                    float q3c = s21*s32 - s22*s31;
                    float q4c = s21*s33 - s23*s31;
                    float q5c = s22*s33 - s23*s32;
                    float det  = p0*q5c - p1*q4c + p2*q3c + p3*q2c - p4*q1c + p5*q0c;
                    float rdet = 1.0f / det;
                    int ia = lane >> 2, ic = lane & 3;   // Inv[ia][ic] = cof(ic,ia)/det
                    int r0 = (ic==0)?1:0, r1 = (ic<=1)?2:1, r2 = (ic<=2)?3:2;
                    int u0 = (ia==0)?1:0, u1 = (ia<=1)?2:1, u2 = (ia<=2)?3:2;
                    float m00=sSig[r0*4+u0], m01=sSig[r0*4+u1], m02=sSig[r0*4+u2];
                    float m10=sSig[r1*4+u0], m11=sSig[r1*4+u1], m12=sSig[r1*4+u2];
                    float m20=sSig[r2*4+u0], m21=sSig[r2*4+u1], m22=sSig[r2*4+u2];
                    float minor = m00*(m11*m22 - m12*m21)
                                - m01*(m10*m22 - m12*m20)
                                + m02*(m10*m21 - m11*m20);
                    float cof = ((ia + ic) & 1) ? -minor : minor;
                    sInv[lane] = cof * rdet;
                }
            }
        }
        if (last) return;
        barrierLds();

        // ---- Phase 3: P = A + Q - (W Inv) W^T (w1, A in regs) ; m_new (w2) ; stage ----
        if (w == 1) {
            float4 inv0 = ld4(&sInv[0]),  inv1 = ld4(&sInv[4]);
            float4 inv2 = ld4(&sInv[8]),  inv3 = ld4(&sInv[12]);
            float4 wj0 = ld4(&sW[(j0+0)*4]);
            float4 wj1 = ld4(&sW[(j0+1)*4]);
            float4 wj2 = ld4(&sW[(j0+2)*4]);
#pragma unroll
            for (int r = 0; r < 3; ++r) {
                float4 wi = ld4(&sW[(i0+r)*4]);
                float4 X  = make_float4(dot4(wi,inv0), dot4(wi,inv1),
                                        dot4(wi,inv2), dot4(wi,inv3));   // Inv symmetric
                sP[(i0+r)*SP + j0+0] = acc[r][0] + sQ[b][(i0+r)*SP + j0+0] - dot4(X, wj0);
                sP[(i0+r)*SP + j0+1] = acc[r][1] + sQ[b][(i0+r)*SP + j0+1] - dot4(X, wj1);
                sP[(i0+r)*SP + j0+2] = acc[r][2] + sQ[b][(i0+r)*SP + j0+2] - dot4(X, wj2);
            }
        } else if (w == 2) {
            if (lane < 24) {            // m_new = Fm + (W Inv) resid
                float4 inv0 = ld4(&sInv[0]),  inv1 = ld4(&sInv[4]);
                float4 inv2 = ld4(&sInv[8]),  inv3 = ld4(&sInv[12]);
                float4 ws = ld4(&sW[lane*4]);
                float4 Xs = make_float4(dot4(ws,inv0), dot4(ws,inv1),
                                        dot4(ws,inv2), dot4(ws,inv3));
                sMean[lane] = sFm[lane] + dot4(Xs, ld4(&sResid[0]));
            }
        }
        // land the t+1 prefetch into the other staging buffer (all threads)
        stage_store(tid, b1, pf0);
        if (tid + 256 < 317) stage_store(tid + 256, b1, pf1);
        barrierLds();
    }
}

extern "C" void kernel_launch(void* const* d_in, const int* in_sizes, int n_in,
                              void* d_out, int out_size, void* d_ws, size_t ws_size,
                              hipStream_t stream) {
    kalman_kernel<<<Gn, 256, 0, stream>>>(
        (const float*)d_in[0], (const float*)d_in[1], (const float*)d_in[2],
        (const float*)d_in[3], (const float*)d_in[4], (const float*)d_in[5],
        (const float*)d_in[6], (float*)d_out);
}